// Round 5
// baseline (704.381 us; speedup 1.0000x reference)
//
#include <hip/hip_runtime.h>
#include <math.h>

typedef float2 c32;

#define NFRAME 256        // B*L
#define FRAME_E 65536     // 64*32*32
#define NTOT 16777216     // NFRAME*FRAME_E

__device__ __forceinline__ void cmadd(float& ar, float& ai, float mr, float mi,
                                      float ur, float ui) {
  ar += mr * ur - mi * ui;
  ai += mr * ui + mi * ur;
}

// ---------------- prep: fold FFT_C into Wb/Wc, build lamb/gamma, DFT tables --
// M layout required by k_gemm: M_arr[c*64 + o] = (W F)[o][c]  (TRANSPOSED!)
__global__ __launch_bounds__(256) void k_prep(
    const float* __restrict__ pl, const float* __restrict__ Wbr,
    const float* __restrict__ Wbi, const float* __restrict__ Wcr,
    const float* __restrict__ Wci, c32* __restrict__ Mb, c32* __restrict__ Mc,
    c32* __restrict__ lamb, float* __restrict__ gam, c32* __restrict__ Ffwd,
    c32* __restrict__ Finv) {
  const float PI = 3.14159265358979323846f;
  int tid = blockIdx.x * 256 + threadIdx.x;
  if (tid < 4096) {                     // (Wb F_C)[o][c] = sum_k Wb[o,k] e^{-2pi i k c/64}
    int o = tid >> 6, c = tid & 63;
    float sr = 0.f, si = 0.f;
    for (int k = 0; k < 64; k++) {
      int m = (k * c) & 63;
      float ang = -(PI / 32.0f) * (float)m;
      float sn, cs; sincosf(ang, &sn, &cs);
      float wr = Wbr[o * 64 + k], wi = Wbi[o * 64 + k];
      sr += wr * cs - wi * sn;
      si += wr * sn + wi * cs;
    }
    Mb[c * 64 + o] = make_float2(sr, si);   // transposed store
  } else if (tid < 8192) {              // (1/64)(Wc F_C^H)[o][c]
    int id = tid - 4096;
    int o = id >> 6, c = id & 63;
    float sr = 0.f, si = 0.f;
    for (int k = 0; k < 64; k++) {
      int m = (k * c) & 63;
      float ang = (PI / 32.0f) * (float)m;
      float sn, cs; sincosf(ang, &sn, &cs);
      float wr = Wcr[o * 64 + k], wi = Wci[o * 64 + k];
      sr += wr * cs - wi * sn;
      si += wr * sn + wi * cs;
    }
    Mc[c * 64 + o] = make_float2(sr * (1.0f / 64.0f), si * (1.0f / 64.0f));  // transposed
  } else if (tid < 10240) {             // lamb[c][hf], gamma[c][hf]
    int id = tid - 8192;
    int c = id >> 5, hf = id & 31;
    float nu = expf(pl[c * 32 + hf]);
    float th = expf(pl[(64 + c) * 32 + hf]);
    float g  = expf(pl[(128 + c) * 32 + hf]);
    float er = expf(-nu);
    float sn, cs; sincosf(th, &sn, &cs);
    lamb[id] = make_float2(er * cs, er * sn);
    gam[id] = g;
  } else if (tid < 11264) {             // Ffwd[hf][h] = e^{-2pi i hf h/32}
    int id = tid - 10240; int a = id >> 5, b = id & 31; int m = (a * b) & 31;
    float ang = -(PI / 16.0f) * (float)m;
    float sn, cs; sincosf(ang, &sn, &cs);
    Ffwd[id] = make_float2(cs, sn);
  } else if (tid < 12288) {             // Finv[y][hf] = (1/32) e^{+2pi i y hf/32}
    int id = tid - 11264; int a = id >> 5, b = id & 31; int m = (a * b) & 31;
    float ang = (PI / 16.0f) * (float)m;
    float sn, cs; sincosf(ang, &sn, &cs);
    Finv[id] = make_float2(cs * (1.0f / 32.0f), sn * (1.0f / 32.0f));
  }
}

// ---------------- forward DFT along H: x[p][h][w] -> u[p][hf][w] ------------
__global__ __launch_bounds__(256) void k_dfth(const float* __restrict__ x,
                                              c32* __restrict__ cbuf,
                                              const c32* __restrict__ Ffwd) {
  __shared__ float xs[32][33];
  __shared__ c32 F4[1024];  // [h][hf0][j] = Ffwd[hf0+8j][h]
  int p = blockIdx.x;
  int t = threadIdx.x;
  const float* xp = x + (size_t)p * 1024;
  for (int i = t; i < 1024; i += 256) {
    xs[i >> 5][i & 31] = xp[i];
    int h = i >> 5, hf0 = (i >> 2) & 7, j = i & 3;
    F4[i] = Ffwd[(hf0 + 8 * j) * 32 + h];
  }
  __syncthreads();
  int w = t & 31, hf0 = t >> 5;
  float ar0 = 0, ai0 = 0, ar1 = 0, ai1 = 0, ar2 = 0, ai2 = 0, ar3 = 0, ai3 = 0;
#pragma unroll 4
  for (int h = 0; h < 32; h++) {
    float xv = xs[h][w];
    const float4* fp = (const float4*)&F4[(h * 8 + hf0) * 4];
    float4 fa = fp[0], fb = fp[1];
    ar0 += fa.x * xv; ai0 += fa.y * xv;
    ar1 += fa.z * xv; ai1 += fa.w * xv;
    ar2 += fb.x * xv; ai2 += fb.y * xv;
    ar3 += fb.z * xv; ai3 += fb.w * xv;
  }
  c32* up = cbuf + (size_t)p * 1024;
  up[(hf0 + 0) * 32 + w]  = make_float2(ar0, ai0);
  up[(hf0 + 8) * 32 + w]  = make_float2(ar1, ai1);
  up[(hf0 + 16) * 32 + w] = make_float2(ar2, ai2);
  up[(hf0 + 24) * 32 + w] = make_float2(ar3, ai3);
}

// ---------------- 64x64 complex channel-mix GEMM, in place ------------------
// out[o][f] = sum_c M[c*64+o] * u[c][f]  (+ bb at w==0, * gamma[o][hf])
__global__ __launch_bounds__(256) void k_gemm(c32* __restrict__ cbuf,
                                              const c32* __restrict__ M,
                                              const float* __restrict__ gam,
                                              const float* __restrict__ bbr,
                                              const float* __restrict__ bbi,
                                              int apply_gb) {
  __shared__ c32 Us[64][64];
  __shared__ c32 Ms[64][64];
  int frame = blockIdx.y;
  int f0 = blockIdx.x * 64;
  int t = threadIdx.x;
  c32* base = cbuf + (size_t)frame * FRAME_E;
  for (int i = t; i < 2048; i += 256) {
    int cc = i >> 5, q = i & 31;
    ((float4*)&Us[cc][0])[q] = *(const float4*)(base + cc * 1024 + f0 + q * 2);
    ((float4*)&Ms[0][0])[i] = ((const float4*)M)[i];
  }
  __syncthreads();
  int og = t >> 4, bg = t & 15;
  int ob = og * 4;
  float accr[4][4], acci[4][4];
#pragma unroll
  for (int i = 0; i < 4; i++)
#pragma unroll
    for (int j = 0; j < 4; j++) { accr[i][j] = 0.f; acci[i][j] = 0.f; }
#pragma unroll 2
  for (int c = 0; c < 64; c++) {
    float4 m01 = ((const float4*)&Ms[c][ob])[0];
    float4 m23 = ((const float4*)&Ms[c][ob])[1];
    float2 u0 = Us[c][bg], u1 = Us[c][bg + 16], u2 = Us[c][bg + 32],
           u3 = Us[c][bg + 48];
    float mr[4] = {m01.x, m01.z, m23.x, m23.z};
    float mi[4] = {m01.y, m01.w, m23.y, m23.w};
    float ur[4] = {u0.x, u1.x, u2.x, u3.x};
    float ui[4] = {u0.y, u1.y, u2.y, u3.y};
#pragma unroll
    for (int i = 0; i < 4; i++)
#pragma unroll
      for (int j = 0; j < 4; j++)
        cmadd(accr[i][j], acci[i][j], mr[i], mi[i], ur[j], ui[j]);
  }
#pragma unroll
  for (int j = 0; j < 4; j++) {
    int f = f0 + bg + 16 * j;
    int hf = f >> 5, w = f & 31;
#pragma unroll
    for (int i = 0; i < 4; i++) {
      int o = ob + i;
      float vr = accr[i][j], vi = acci[i][j];
      if (apply_gb) {
        if (w == 0) { vr += bbr[o]; vi += bbi[o]; }
        float g = gam[o * 32 + hf];
        vr *= g; vi *= g;
      }
      base[o * 1024 + f] = make_float2(vr, vi);
    }
  }
}

// ---------------- linear recurrence over L, in place ------------------------
__global__ __launch_bounds__(256) void k_scan(c32* __restrict__ cbuf,
                                              const c32* __restrict__ lamb) {
  int q = blockIdx.x * 256 + threadIdx.x;  // 0..131071
  int b = q >> 16, e = q & 65535;
  int c = e >> 10, hf = (e >> 5) & 31;
  float2 L = lamb[c * 32 + hf];
  float ar = 0.f, ai = 0.f;
  c32* p = cbuf + (size_t)b * 128 * FRAME_E + e;
#pragma unroll 4
  for (int l = 0; l < 128; l++) {
    float2 v = p[(size_t)l * FRAME_E];
    float nr = L.x * ar - L.y * ai + v.x;
    float ni = L.x * ai + L.y * ar + v.y;
    ar = nr; ai = ni;
    p[(size_t)l * FRAME_E] = make_float2(ar, ai);
  }
}

// ---------------- last_hidden: FFT along W of scan output at l=127 ----------
// Real-cast output: out2[idx] = Re(lh[b,0,c,hf,wf]), 131072 floats total.
__global__ __launch_bounds__(256) void k_last2(const c32* __restrict__ cbuf,
                                               float* __restrict__ out2) {
  const float PI = 3.14159265358979323846f;
  int idx = blockIdx.x * 256 + threadIdx.x;  // [0, 131072)
  int wf = idx & 31;
  int hf = (idx >> 5) & 31;
  int c  = (idx >> 10) & 63;
  int b  = idx >> 16;
  const c32* s = cbuf + (size_t)(b * 128 + 127) * FRAME_E + c * 1024 + hf * 32;
  float sr = 0.f;
  for (int w2 = 0; w2 < 32; w2++) {
    float2 v = s[w2];
    int m = (w2 * wf) & 31;
    float ang = -(PI / 16.0f) * (float)m;  // e^{-2pi i w2*wf/32}
    float sn, cs; sincosf(ang, &sn, &cs);
    sr += v.x * cs - v.y * sn;
  }
  out2[idx] = sr;
}

// ---------------- inverse DFT along H + real + bc_r -------------------------
__global__ __launch_bounds__(256) void k_idft(const c32* __restrict__ cbuf,
                                              float* __restrict__ out1,
                                              const c32* __restrict__ Finv,
                                              const float* __restrict__ bcr) {
  __shared__ c32 Ts[32][32];
  __shared__ c32 F4[1024];  // [hf][y0][j] = Finv[y0+8j][hf]
  int p = blockIdx.x;       // frame*64 + o
  int t = threadIdx.x;
  const c32* tp = cbuf + (size_t)p * 1024;
  for (int i = t; i < 1024; i += 256) {
    Ts[i >> 5][i & 31] = tp[i];
    int hf = i >> 5, y0 = (i >> 2) & 7, j = i & 3;
    F4[i] = Finv[(y0 + 8 * j) * 32 + hf];
  }
  __syncthreads();
  int w = t & 31, y0 = t >> 5;
  float bias = bcr[p & 63];
  float a0 = bias, a1 = bias, a2 = bias, a3 = bias;
#pragma unroll 4
  for (int hf = 0; hf < 32; hf++) {
    float2 tv = Ts[hf][w];
    const float4* fp = (const float4*)&F4[(hf * 8 + y0) * 4];
    float4 fa = fp[0], fb = fp[1];
    a0 += fa.x * tv.x - fa.y * tv.y;
    a1 += fa.z * tv.x - fa.w * tv.y;
    a2 += fb.x * tv.x - fb.y * tv.y;
    a3 += fb.z * tv.x - fb.w * tv.y;
  }
  float* op = out1 + (size_t)p * 1024;
  op[(y0 + 0) * 32 + w]  = a0;
  op[(y0 + 8) * 32 + w]  = a1;
  op[(y0 + 16) * 32 + w] = a2;
  op[(y0 + 24) * 32 + w] = a3;
}

// ---------------- LayerNorm over (C,H,W) + residual, in place in d_out ------
__global__ __launch_bounds__(1024) void k_ln(float* __restrict__ out1,
                                             const float* __restrict__ x,
                                             const float* __restrict__ lw,
                                             const float* __restrict__ lb) {
  __shared__ float red[32];
  int fm = blockIdx.x;
  int t = threadIdx.x;
  float* r = out1 + (size_t)fm * FRAME_E;
  const float* xp = x + (size_t)fm * FRAME_E;
  float s1 = 0.f, s2 = 0.f;
  for (int i = t; i < 16384; i += 1024) {
    float4 v = ((const float4*)r)[i];
    s1 += v.x + v.y + v.z + v.w;
    s2 += v.x * v.x + v.y * v.y + v.z * v.z + v.w * v.w;
  }
#pragma unroll
  for (int off = 32; off > 0; off >>= 1) {
    s1 += __shfl_down(s1, off);
    s2 += __shfl_down(s2, off);
  }
  int wid = t >> 6, lane = t & 63;
  if (lane == 0) { red[wid] = s1; red[16 + wid] = s2; }
  __syncthreads();
  if (t == 0) {
    float a = 0.f, b2 = 0.f;
    for (int i = 0; i < 16; i++) { a += red[i]; b2 += red[16 + i]; }
    float mean = a * (1.0f / 65536.0f);
    float var = b2 * (1.0f / 65536.0f) - mean * mean;
    if (var < 0.f) var = 0.f;
    red[0] = mean;
    red[1] = rsqrtf(var + 1e-5f);
  }
  __syncthreads();
  float mean = red[0], rstd = red[1];
  for (int i = t; i < 16384; i += 1024) {
    float4 v = ((const float4*)r)[i];
    float4 wv = ((const float4*)lw)[i];
    float4 bv = ((const float4*)lb)[i];
    float4 xv = ((const float4*)xp)[i];
    float4 o;
    o.x = (v.x - mean) * rstd * wv.x + bv.x + xv.x;
    o.y = (v.y - mean) * rstd * wv.y + bv.y + xv.y;
    o.z = (v.z - mean) * rstd * wv.z + bv.z + xv.z;
    o.w = (v.w - mean) * rstd * wv.w + bv.w + xv.w;
    ((float4*)r)[i] = o;
  }
}

extern "C" void kernel_launch(void* const* d_in, const int* in_sizes, int n_in,
                              void* d_out, int out_size, void* d_ws,
                              size_t ws_size, hipStream_t stream) {
  const float* x   = (const float*)d_in[0];
  const float* pl  = (const float*)d_in[1];
  const float* Wbr = (const float*)d_in[2];
  const float* Wbi = (const float*)d_in[3];
  const float* bbr = (const float*)d_in[4];
  const float* bbi = (const float*)d_in[5];
  const float* Wcr = (const float*)d_in[6];
  const float* Wci = (const float*)d_in[7];
  const float* bcr = (const float*)d_in[8];
  // d_in[9] = bc_i: unused (imag part discarded by .real)
  const float* lw  = (const float*)d_in[10];
  const float* lb  = (const float*)d_in[11];

  float* out1 = (float*)d_out;
  float* out2 = out1 + NTOT;  // real-cast last_hidden: 131072 floats

  c32* cbuf  = (c32*)d_ws;        // 16,777,216 c32 = 134 MB
  c32* Mb    = cbuf + NTOT;       // 4096
  c32* Mc    = Mb + 4096;         // 4096
  c32* lamb  = Mc + 4096;         // 2048
  float* gam = (float*)(lamb + 2048);  // 2048 floats
  c32* Ffwd  = (c32*)(gam + 2048);     // 1024
  c32* Finv  = Ffwd + 1024;            // 1024

  k_prep<<<48, 256, 0, stream>>>(pl, Wbr, Wbi, Wcr, Wci, Mb, Mc, lamb, gam,
                                 Ffwd, Finv);
  k_dfth<<<16384, 256, 0, stream>>>(x, cbuf, Ffwd);
  k_gemm<<<dim3(16, 256), 256, 0, stream>>>(cbuf, Mb, gam, bbr, bbi, 1);
  k_scan<<<512, 256, 0, stream>>>(cbuf, lamb);
  k_last2<<<512, 256, 0, stream>>>(cbuf, out2);
  k_gemm<<<dim3(16, 256), 256, 0, stream>>>(cbuf, Mc, gam, bbr, bbi, 0);
  k_idft<<<16384, 256, 0, stream>>>(cbuf, out1, Finv, bcr);
  k_ln<<<256, 1024, 0, stream>>>(out1, x, lw, lb);
}

// Round 6
// 392.209 us; speedup vs baseline: 1.7959x; 1.7959x over previous
//
#include <hip/hip_runtime.h>
#include <math.h>

typedef float2 c32;
typedef short bf16x8 __attribute__((ext_vector_type(8)));
typedef float f32x4 __attribute__((ext_vector_type(4)));

#define NFRAME 256        // B*L
#define FRAME_E 65536     // 64*32*32
#define NTOT 16777216     // NFRAME*FRAME_E

__device__ __forceinline__ unsigned short f2bf(float f) {
  unsigned int u = __float_as_uint(f);
  return (unsigned short)((u + 0x7fffu + ((u >> 16) & 1u)) >> 16);
}
__device__ __forceinline__ float bf2f_lo(unsigned int v) {
  return __uint_as_float(v << 16);
}
__device__ __forceinline__ float bf2f_hi(unsigned int v) {
  return __uint_as_float(v & 0xffff0000u);
}
__device__ __forceinline__ unsigned int packbf(float r, float i) {
  return (unsigned int)f2bf(r) | ((unsigned int)f2bf(i) << 16);
}

// ---------------- prep: fold FFT_C into Wb/Wc (bf16 planes), lamb/gamma, DFT tables
__global__ __launch_bounds__(256) void k_prep(
    const float* __restrict__ pl, const float* __restrict__ Wbr,
    const float* __restrict__ Wbi, const float* __restrict__ Wcr,
    const float* __restrict__ Wci, unsigned short* __restrict__ MbR,
    unsigned short* __restrict__ MbI, unsigned short* __restrict__ MbN,
    unsigned short* __restrict__ McR, unsigned short* __restrict__ McI,
    unsigned short* __restrict__ McN, c32* __restrict__ lamb,
    float* __restrict__ gam, c32* __restrict__ Ffwd, c32* __restrict__ Finv) {
  const float PI = 3.14159265358979323846f;
  int tid = blockIdx.x * 256 + threadIdx.x;
  if (tid < 4096) {          // (Wb F_C)[o][c] = sum_k Wb[o,k] e^{-2pi i k c/64}
    int o = tid >> 6, c = tid & 63;
    float sr = 0.f, si = 0.f;
    for (int k = 0; k < 64; k++) {
      int m = (k * c) & 63;
      float ang = -(PI / 32.0f) * (float)m;
      float sn, cs; sincosf(ang, &sn, &cs);
      float wr = Wbr[o * 64 + k], wi = Wbi[o * 64 + k];
      sr += wr * cs - wi * sn;
      si += wr * sn + wi * cs;
    }
    MbR[tid] = f2bf(sr); MbI[tid] = f2bf(si); MbN[tid] = f2bf(-si);
  } else if (tid < 8192) {   // (1/64)(Wc F_C^H)[o][c]
    int id = tid - 4096;
    int o = id >> 6, c = id & 63;
    float sr = 0.f, si = 0.f;
    for (int k = 0; k < 64; k++) {
      int m = (k * c) & 63;
      float ang = (PI / 32.0f) * (float)m;
      float sn, cs; sincosf(ang, &sn, &cs);
      float wr = Wcr[o * 64 + k], wi = Wci[o * 64 + k];
      sr += wr * cs - wi * sn;
      si += wr * sn + wi * cs;
    }
    sr *= (1.0f / 64.0f); si *= (1.0f / 64.0f);
    McR[id] = f2bf(sr); McI[id] = f2bf(si); McN[id] = f2bf(-si);
  } else if (tid < 10240) {  // lamb[c][hf], gamma[c][hf]
    int id = tid - 8192;
    int c = id >> 5, hf = id & 31;
    float nu = expf(pl[c * 32 + hf]);
    float th = expf(pl[(64 + c) * 32 + hf]);
    float g  = expf(pl[(128 + c) * 32 + hf]);
    float er = expf(-nu);
    float sn, cs; sincosf(th, &sn, &cs);
    lamb[id] = make_float2(er * cs, er * sn);
    gam[id] = g;
  } else if (tid < 11264) {  // Ffwd[hf][h] = e^{-2pi i hf h/32}
    int id = tid - 10240; int a = id >> 5, b = id & 31; int m = (a * b) & 31;
    float ang = -(PI / 16.0f) * (float)m;
    float sn, cs; sincosf(ang, &sn, &cs);
    Ffwd[id] = make_float2(cs, sn);
  } else if (tid < 12288) {  // Finv[y][hf] = (1/32) e^{+2pi i y hf/32}
    int id = tid - 11264; int a = id >> 5, b = id & 31; int m = (a * b) & 31;
    float ang = (PI / 16.0f) * (float)m;
    float sn, cs; sincosf(ang, &sn, &cs);
    Finv[id] = make_float2(cs * (1.0f / 32.0f), sn * (1.0f / 32.0f));
  }
}

// ---------------- forward DFT along H: x[p][h][w] -> u[p][w][hf] (packed bf16c)
__global__ __launch_bounds__(256) void k_dfth(const float* __restrict__ x,
                                              unsigned int* __restrict__ ubuf,
                                              const c32* __restrict__ Ffwd) {
  __shared__ float xs[32][33];
  __shared__ __align__(16) c32 F4[1024];  // [h][hf0][j] = Ffwd[hf0+8j][h]
  __shared__ unsigned int us[32 * 33];    // [w][hf] padded
  int p = blockIdx.x;
  int t = threadIdx.x;
  const float* xp = x + (size_t)p * 1024;
  for (int i = t; i < 1024; i += 256) {
    xs[i >> 5][i & 31] = xp[i];
    int h = i >> 5, hf0 = (i >> 2) & 7, j = i & 3;
    F4[i] = Ffwd[(hf0 + 8 * j) * 32 + h];
  }
  __syncthreads();
  int w = t & 31, hf0 = t >> 5;
  float ar0 = 0, ai0 = 0, ar1 = 0, ai1 = 0, ar2 = 0, ai2 = 0, ar3 = 0, ai3 = 0;
#pragma unroll 4
  for (int h = 0; h < 32; h++) {
    float xv = xs[h][w];
    const float4* fp = (const float4*)&F4[(h * 8 + hf0) * 4];
    float4 fa = fp[0], fb = fp[1];
    ar0 += fa.x * xv; ai0 += fa.y * xv;
    ar1 += fa.z * xv; ai1 += fa.w * xv;
    ar2 += fb.x * xv; ai2 += fb.y * xv;
    ar3 += fb.z * xv; ai3 += fb.w * xv;
  }
  us[w * 33 + hf0 + 0]  = packbf(ar0, ai0);
  us[w * 33 + hf0 + 8]  = packbf(ar1, ai1);
  us[w * 33 + hf0 + 16] = packbf(ar2, ai2);
  us[w * 33 + hf0 + 24] = packbf(ar3, ai3);
  __syncthreads();
  unsigned int* up = ubuf + (size_t)p * 1024;
#pragma unroll
  for (int k = 0; k < 4; k++) {
    int idx = t + 256 * k;
    up[idx] = us[(idx >> 5) * 33 + (idx & 31)];
  }
}

// ---------------- MFMA 64x64 complex channel-mix: dst[o][f'] = sum_c M[o][c] src[c][f']
// src/dst packed bf16c, per-frame layout [ch][f'=w*32+hf].
// apply_gb: dst = gamma[o][hf] * (prod + bb[o]*delta_{w==0})
__global__ __launch_bounds__(256) void k_gemm(const unsigned int* __restrict__ src,
                                              unsigned int* __restrict__ dst,
                                              const unsigned short* __restrict__ Mr,
                                              const unsigned short* __restrict__ Mi,
                                              const unsigned short* __restrict__ Mn,
                                              const float* __restrict__ gam,
                                              const float* __restrict__ bbr,
                                              const float* __restrict__ bbi,
                                              int apply_gb) {
  __shared__ __align__(16) short Ams[3][64][72];  // [Re, Im, -Im][o][c]
  __shared__ __align__(16) short Bs[2][64][72];   // [re, im][f'][c]
  int frame = blockIdx.y;
  int f0 = blockIdx.x * 64;
  int t = threadIdx.x;
  // stage M planes (3 x 64 x 64 bf16) as 16B chunks
  for (int j = t; j < 1536; j += 256) {
    int plane = j >> 9, idx = j & 511;
    int o = idx >> 3, seg = idx & 7;
    const unsigned short* ms = (plane == 0) ? Mr : (plane == 1) ? Mi : Mn;
    *(uint4*)&Ams[plane][o][seg * 8] = *(const uint4*)(ms + o * 64 + seg * 8);
  }
  // stage u block: rows c=0..63, cols f0..f0+63, unpack to re/im planes transposed
  {
    const unsigned int* ub = src + (size_t)frame * FRAME_E + f0 + (t & 63) * 1024;
    int q = t >> 6;  // wave id -> f' quad group
#pragma unroll
    for (int i = 0; i < 4; i++) {
      uint4 v4 = *(const uint4*)(ub + q * 16 + i * 4);
      int fr = q * 16 + i * 4;
      int c = t & 63;
      unsigned int vv[4] = {v4.x, v4.y, v4.z, v4.w};
#pragma unroll
      for (int k = 0; k < 4; k++) {
        Bs[0][fr + k][c] = (short)(vv[k] & 0xffffu);
        Bs[1][fr + k][c] = (short)(vv[k] >> 16);
      }
    }
  }
  __syncthreads();
  int l = t & 63, wv = t >> 6;
  int n0 = wv * 16;
  int lrow = l & 15, loct = l >> 4;
  f32x4 accR[4], accI[4];
#pragma unroll
  for (int mt = 0; mt < 4; mt++) {
    accR[mt] = (f32x4){0.f, 0.f, 0.f, 0.f};
    accI[mt] = (f32x4){0.f, 0.f, 0.f, 0.f};
  }
#pragma unroll
  for (int kt = 0; kt < 2; kt++) {
    bf16x8 br = *(const bf16x8*)&Bs[0][n0 + lrow][kt * 32 + loct * 8];
    bf16x8 bi = *(const bf16x8*)&Bs[1][n0 + lrow][kt * 32 + loct * 8];
#pragma unroll
    for (int mt = 0; mt < 4; mt++) {
      bf16x8 ar = *(const bf16x8*)&Ams[0][mt * 16 + lrow][kt * 32 + loct * 8];
      bf16x8 ai = *(const bf16x8*)&Ams[1][mt * 16 + lrow][kt * 32 + loct * 8];
      bf16x8 an = *(const bf16x8*)&Ams[2][mt * 16 + lrow][kt * 32 + loct * 8];
      accR[mt] = __builtin_amdgcn_mfma_f32_16x16x32_bf16(ar, br, accR[mt], 0, 0, 0);
      accR[mt] = __builtin_amdgcn_mfma_f32_16x16x32_bf16(an, bi, accR[mt], 0, 0, 0);
      accI[mt] = __builtin_amdgcn_mfma_f32_16x16x32_bf16(ai, br, accI[mt], 0, 0, 0);
      accI[mt] = __builtin_amdgcn_mfma_f32_16x16x32_bf16(ar, bi, accI[mt], 0, 0, 0);
    }
  }
  // epilogue: C layout col = l&15, row = (l>>4)*4 + reg  (o within m-tile)
  unsigned int* db = dst + (size_t)frame * FRAME_E;
  int col = f0 + n0 + lrow;
  int hf = col & 31, w = col >> 5;
#pragma unroll
  for (int mt = 0; mt < 4; mt++) {
#pragma unroll
    for (int r = 0; r < 4; r++) {
      int o = mt * 16 + loct * 4 + r;
      float vr = accR[mt][r], vi = accI[mt][r];
      if (apply_gb) {
        if (w == 0) { vr += bbr[o]; vi += bbi[o]; }
        float g = gam[o * 32 + hf];
        vr *= g; vi *= g;
      }
      db[o * 1024 + col] = packbf(vr, vi);
    }
  }
}

// ---------------- linear recurrence over L, in place (packed bf16c, fp32 state)
__global__ __launch_bounds__(256) void k_scan(unsigned int* __restrict__ buf,
                                              const c32* __restrict__ lamb) {
  int q = blockIdx.x * 256 + threadIdx.x;  // 0..131071
  int b = q >> 16, e = q & 65535;
  int c = e >> 10, hf = e & 31;
  float2 L = lamb[c * 32 + hf];
  float ar = 0.f, ai = 0.f;
  unsigned int* p = buf + (size_t)b * 128 * FRAME_E + e;
#pragma unroll 8
  for (int l = 0; l < 128; l++) {
    unsigned int v = p[(size_t)l * FRAME_E];
    float nr = L.x * ar - L.y * ai + bf2f_lo(v);
    float ni = L.x * ai + L.y * ar + bf2f_hi(v);
    ar = nr; ai = ni;
    p[(size_t)l * FRAME_E] = packbf(ar, ai);
  }
}

// ---------------- last_hidden: DFT along W of state at l=127, real part only
__global__ __launch_bounds__(256) void k_last2(const unsigned int* __restrict__ buf,
                                               float* __restrict__ out2) {
  const float PI = 3.14159265358979323846f;
  int idx = blockIdx.x * 256 + threadIdx.x;  // [0, 131072)
  int wf = idx & 31;
  int hf = (idx >> 5) & 31;
  int c  = (idx >> 10) & 63;
  int b  = idx >> 16;
  const unsigned int* s =
      buf + (size_t)(b * 128 + 127) * FRAME_E + c * 1024 + hf;
  float sr = 0.f;
  for (int w2 = 0; w2 < 32; w2++) {
    unsigned int v = s[w2 * 32];
    int m = (w2 * wf) & 31;
    float ang = -(PI / 16.0f) * (float)m;
    float sn, cs; sincosf(ang, &sn, &cs);
    sr += bf2f_lo(v) * cs - bf2f_hi(v) * sn;
  }
  out2[idx] = sr;
}

// ---------------- inverse DFT along H + real + bc_r -------------------------
// input t packed bf16c [frame*64+o][w*32+hf] -> out1[frame*64+o][y*32+w]
__global__ __launch_bounds__(256) void k_idft(const unsigned int* __restrict__ tbuf,
                                              float* __restrict__ out1,
                                              const c32* __restrict__ Finv,
                                              const float* __restrict__ bcr) {
  __shared__ float2 Ts[32][33];            // [hf][w]
  __shared__ __align__(16) c32 F4[1024];   // [hf][y0][j] = Finv[y0+8j][hf]
  int p = blockIdx.x;  // frame*64 + o
  int t = threadIdx.x;
  const unsigned int* tp = tbuf + (size_t)p * 1024;
  for (int i = t; i < 1024; i += 256) {
    unsigned int v = tp[i];
    Ts[i & 31][i >> 5] = make_float2(bf2f_lo(v), bf2f_hi(v));  // i = w*32+hf
    int hf = i >> 5, y0 = (i >> 2) & 7, j = i & 3;
    F4[i] = Finv[(y0 + 8 * j) * 32 + hf];
  }
  __syncthreads();
  int w = t & 31, y0 = t >> 5;
  float bias = bcr[p & 63];
  float a0 = bias, a1 = bias, a2 = bias, a3 = bias;
#pragma unroll 4
  for (int hf = 0; hf < 32; hf++) {
    float2 tv = Ts[hf][w];
    const float4* fp = (const float4*)&F4[(hf * 8 + y0) * 4];
    float4 fa = fp[0], fb = fp[1];
    a0 += fa.x * tv.x - fa.y * tv.y;
    a1 += fa.z * tv.x - fa.w * tv.y;
    a2 += fb.x * tv.x - fb.y * tv.y;
    a3 += fb.z * tv.x - fb.w * tv.y;
  }
  float* op = out1 + (size_t)p * 1024;
  op[(y0 + 0) * 32 + w]  = a0;
  op[(y0 + 8) * 32 + w]  = a1;
  op[(y0 + 16) * 32 + w] = a2;
  op[(y0 + 24) * 32 + w] = a3;
}

// ---------------- LayerNorm over (C,H,W) + residual, in place in d_out ------
__global__ __launch_bounds__(1024) void k_ln(float* __restrict__ out1,
                                             const float* __restrict__ x,
                                             const float* __restrict__ lw,
                                             const float* __restrict__ lb) {
  __shared__ float red[32];
  int fm = blockIdx.x;
  int t = threadIdx.x;
  float* r = out1 + (size_t)fm * FRAME_E;
  const float* xp = x + (size_t)fm * FRAME_E;
  float s1 = 0.f, s2 = 0.f;
  for (int i = t; i < 16384; i += 1024) {
    float4 v = ((const float4*)r)[i];
    s1 += v.x + v.y + v.z + v.w;
    s2 += v.x * v.x + v.y * v.y + v.z * v.z + v.w * v.w;
  }
#pragma unroll
  for (int off = 32; off > 0; off >>= 1) {
    s1 += __shfl_down(s1, off);
    s2 += __shfl_down(s2, off);
  }
  int wid = t >> 6, lane = t & 63;
  if (lane == 0) { red[wid] = s1; red[16 + wid] = s2; }
  __syncthreads();
  if (t == 0) {
    float a = 0.f, b2 = 0.f;
    for (int i = 0; i < 16; i++) { a += red[i]; b2 += red[16 + i]; }
    float mean = a * (1.0f / 65536.0f);
    float var = b2 * (1.0f / 65536.0f) - mean * mean;
    if (var < 0.f) var = 0.f;
    red[0] = mean;
    red[1] = rsqrtf(var + 1e-5f);
  }
  __syncthreads();
  float mean = red[0], rstd = red[1];
  for (int i = t; i < 16384; i += 1024) {
    float4 v = ((const float4*)r)[i];
    float4 wv = ((const float4*)lw)[i];
    float4 bv = ((const float4*)lb)[i];
    float4 xv = ((const float4*)xp)[i];
    float4 o;
    o.x = (v.x - mean) * rstd * wv.x + bv.x + xv.x;
    o.y = (v.y - mean) * rstd * wv.y + bv.y + xv.y;
    o.z = (v.z - mean) * rstd * wv.z + bv.z + xv.z;
    o.w = (v.w - mean) * rstd * wv.w + bv.w + xv.w;
    ((float4*)r)[i] = o;
  }
}

extern "C" void kernel_launch(void* const* d_in, const int* in_sizes, int n_in,
                              void* d_out, int out_size, void* d_ws,
                              size_t ws_size, hipStream_t stream) {
  const float* x   = (const float*)d_in[0];
  const float* pl  = (const float*)d_in[1];
  const float* Wbr = (const float*)d_in[2];
  const float* Wbi = (const float*)d_in[3];
  const float* bbr = (const float*)d_in[4];
  const float* bbi = (const float*)d_in[5];
  const float* Wcr = (const float*)d_in[6];
  const float* Wci = (const float*)d_in[7];
  const float* bcr = (const float*)d_in[8];
  // d_in[9] = bc_i: unused (imag discarded by .real)
  const float* lw  = (const float*)d_in[10];
  const float* lb  = (const float*)d_in[11];

  float* out1 = (float*)d_out;
  float* out2 = out1 + NTOT;  // real-cast last_hidden: 131072 floats

  unsigned int* A = (unsigned int*)d_ws;  // 67.1 MB packed bf16c
  unsigned int* B = A + NTOT;             // 67.1 MB packed bf16c
  unsigned short* MbR = (unsigned short*)(B + NTOT);
  unsigned short* MbI = MbR + 4096;
  unsigned short* MbN = MbI + 4096;
  unsigned short* McR = MbN + 4096;
  unsigned short* McI = McR + 4096;
  unsigned short* McN = McI + 4096;
  c32* lamb  = (c32*)(McN + 4096);
  float* gam = (float*)(lamb + 2048);
  c32* Ffwd  = (c32*)(gam + 2048);
  c32* Finv  = Ffwd + 1024;

  k_prep<<<48, 256, 0, stream>>>(pl, Wbr, Wbi, Wcr, Wci, MbR, MbI, MbN, McR,
                                 McI, McN, lamb, gam, Ffwd, Finv);
  k_dfth<<<16384, 256, 0, stream>>>(x, A, Ffwd);
  k_gemm<<<dim3(16, 256), 256, 0, stream>>>(A, B, MbR, MbI, MbN, gam, bbr,
                                            bbi, 1);
  k_scan<<<512, 256, 0, stream>>>(B, lamb);
  k_last2<<<512, 256, 0, stream>>>(B, out2);
  k_gemm<<<dim3(16, 256), 256, 0, stream>>>(B, A, McR, McI, McN, gam, bbr,
                                            bbi, 0);
  k_idft<<<16384, 256, 0, stream>>>(A, out1, Finv, bcr);
  k_ln<<<256, 1024, 0, stream>>>(out1, x, lw, lb);
}

// Round 8
// 346.840 us; speedup vs baseline: 2.0309x; 1.1308x over previous
//
#include <hip/hip_runtime.h>
#include <math.h>

typedef float2 c32;
typedef short bf16x8 __attribute__((ext_vector_type(8)));
typedef float f32x4 __attribute__((ext_vector_type(4)));

#define NFRAME 256        // B*L
#define FRAME_E 65536     // 64*32*32
#define NTOT 16777216     // NFRAME*FRAME_E

__device__ __forceinline__ unsigned short f2bf(float f) {
  unsigned int u = __float_as_uint(f);
  return (unsigned short)((u + 0x7fffu + ((u >> 16) & 1u)) >> 16);
}
__device__ __forceinline__ float bf2f_lo(unsigned int v) {
  return __uint_as_float(v << 16);
}
__device__ __forceinline__ float bf2f_hi(unsigned int v) {
  return __uint_as_float(v & 0xffff0000u);
}
__device__ __forceinline__ unsigned int packbf(float r, float i) {
  return (unsigned int)f2bf(r) | ((unsigned int)f2bf(i) << 16);
}

// ---------------- prep: fold FFT_C into Wb/Wc (bf16 planes), lamb/gamma, tables
__global__ __launch_bounds__(256) void k_prep(
    const float* __restrict__ pl, const float* __restrict__ Wbr,
    const float* __restrict__ Wbi, const float* __restrict__ Wcr,
    const float* __restrict__ Wci, unsigned short* __restrict__ MbR,
    unsigned short* __restrict__ MbI, unsigned short* __restrict__ MbN,
    unsigned short* __restrict__ McR, unsigned short* __restrict__ McI,
    unsigned short* __restrict__ McN, c32* __restrict__ lamb,
    float* __restrict__ gam, c32* __restrict__ Ffwd,
    unsigned short* __restrict__ FIr, unsigned short* __restrict__ FIn) {
  const float PI = 3.14159265358979323846f;
  int tid = blockIdx.x * 256 + threadIdx.x;
  if (tid < 4096) {          // (Wb F_C)[o][c]
    int o = tid >> 6, c = tid & 63;
    float sr = 0.f, si = 0.f;
    for (int k = 0; k < 64; k++) {
      int m = (k * c) & 63;
      float ang = -(PI / 32.0f) * (float)m;
      float sn, cs; sincosf(ang, &sn, &cs);
      float wr = Wbr[o * 64 + k], wi = Wbi[o * 64 + k];
      sr += wr * cs - wi * sn;
      si += wr * sn + wi * cs;
    }
    MbR[tid] = f2bf(sr); MbI[tid] = f2bf(si); MbN[tid] = f2bf(-si);
  } else if (tid < 8192) {   // (1/64)(Wc F_C^H)[o][c]
    int id = tid - 4096;
    int o = id >> 6, c = id & 63;
    float sr = 0.f, si = 0.f;
    for (int k = 0; k < 64; k++) {
      int m = (k * c) & 63;
      float ang = (PI / 32.0f) * (float)m;
      float sn, cs; sincosf(ang, &sn, &cs);
      float wr = Wcr[o * 64 + k], wi = Wci[o * 64 + k];
      sr += wr * cs - wi * sn;
      si += wr * sn + wi * cs;
    }
    sr *= (1.0f / 64.0f); si *= (1.0f / 64.0f);
    McR[id] = f2bf(sr); McI[id] = f2bf(si); McN[id] = f2bf(-si);
  } else if (tid < 10240) {  // lamb[c][hf], gamma[c][hf]
    int id = tid - 8192;
    int c = id >> 5, hf = id & 31;
    float nu = expf(pl[c * 32 + hf]);
    float th = expf(pl[(64 + c) * 32 + hf]);
    float g  = expf(pl[(128 + c) * 32 + hf]);
    float er = expf(-nu);
    float sn, cs; sincosf(th, &sn, &cs);
    lamb[id] = make_float2(er * cs, er * sn);
    gam[id] = g;
  } else if (tid < 11264) {  // Ffwd[hf][h] = e^{-2pi i hf h/32}
    int id = tid - 10240; int a = id >> 5, b = id & 31; int m = (a * b) & 31;
    float ang = -(PI / 16.0f) * (float)m;
    float sn, cs; sincosf(ang, &sn, &cs);
    Ffwd[id] = make_float2(cs, sn);
  } else if (tid < 12288) {  // FIr/FIn[y][hf]: (1/32) e^{+2pi i y hf/32}, neg-imag plane
    int id = tid - 11264; int a = id >> 5, b = id & 31; int m = (a * b) & 31;
    float ang = (PI / 16.0f) * (float)m;
    float sn, cs; sincosf(ang, &sn, &cs);
    FIr[id] = f2bf(cs * (1.0f / 32.0f));
    FIn[id] = f2bf(-sn * (1.0f / 32.0f));
  }
}

// ---------------- forward DFT along H: x[p][h][w] -> u[p][w*32+hf] (packed bf16c)
__global__ __launch_bounds__(256) void k_dfth(const float* __restrict__ x,
                                              unsigned int* __restrict__ ubuf,
                                              const c32* __restrict__ Ffwd) {
  __shared__ float xs[32][33];
  __shared__ __align__(16) c32 F4[1024];  // [h][hf0][j] = Ffwd[hf0+8j][h]
  __shared__ unsigned int us[32 * 33];    // [w][hf] padded
  int p = blockIdx.x;
  int t = threadIdx.x;
  const float* xp = x + (size_t)p * 1024;
  for (int i = t; i < 1024; i += 256) {
    xs[i >> 5][i & 31] = xp[i];
    int h = i >> 5, hf0 = (i >> 2) & 7, j = i & 3;
    F4[i] = Ffwd[(hf0 + 8 * j) * 32 + h];
  }
  __syncthreads();
  int w = t & 31, hf0 = t >> 5;
  float ar0 = 0, ai0 = 0, ar1 = 0, ai1 = 0, ar2 = 0, ai2 = 0, ar3 = 0, ai3 = 0;
#pragma unroll 4
  for (int h = 0; h < 32; h++) {
    float xv = xs[h][w];
    const float4* fp = (const float4*)&F4[(h * 8 + hf0) * 4];
    float4 fa = fp[0], fb = fp[1];
    ar0 += fa.x * xv; ai0 += fa.y * xv;
    ar1 += fa.z * xv; ai1 += fa.w * xv;
    ar2 += fb.x * xv; ai2 += fb.y * xv;
    ar3 += fb.z * xv; ai3 += fb.w * xv;
  }
  us[w * 33 + hf0 + 0]  = packbf(ar0, ai0);
  us[w * 33 + hf0 + 8]  = packbf(ar1, ai1);
  us[w * 33 + hf0 + 16] = packbf(ar2, ai2);
  us[w * 33 + hf0 + 24] = packbf(ar3, ai3);
  __syncthreads();
  unsigned int* up = ubuf + (size_t)p * 1024;
#pragma unroll
  for (int k = 0; k < 4; k++) {
    int idx = t + 256 * k;
    up[idx] = us[(idx >> 5) * 33 + (idx & 31)];
  }
}

// ---------------- MFMA 64x64 complex channel-mix + (gemm2) freq-domain LN stats
// dst[o][f'] = sum_c M[o][c] src[c][f']; f' = w*32+hf
// apply_gb: += bb[o] at w==0, then * gamma[o][hf].  !apply_gb: accumulate LN stats.
__global__ __launch_bounds__(256) void k_gemm(const unsigned int* __restrict__ src,
                                              unsigned int* __restrict__ dst,
                                              const unsigned short* __restrict__ Mr,
                                              const unsigned short* __restrict__ Mi,
                                              const unsigned short* __restrict__ Mn,
                                              const float* __restrict__ gam,
                                              const float* __restrict__ bbr,
                                              const float* __restrict__ bbi,
                                              const float* __restrict__ bcr,
                                              float* __restrict__ statsRaw,
                                              int apply_gb) {
  __shared__ __align__(16) short sm[23040];  // 46 KB
  short (*Ams)[64][72] = (short (*)[64][72])sm;           // 3 planes
  short (*Bs)[64][72]  = (short (*)[64][72])(sm + 13824); // 2 planes
  int frame = blockIdx.y;
  int f0 = blockIdx.x * 64;
  int t = threadIdx.x;
  for (int j = t; j < 1536; j += 256) {
    int plane = j >> 9, idx = j & 511;
    int o = idx >> 3, seg = idx & 7;
    const unsigned short* ms = (plane == 0) ? Mr : (plane == 1) ? Mi : Mn;
    *(uint4*)&Ams[plane][o][seg * 8] = *(const uint4*)(ms + o * 64 + seg * 8);
  }
  {
    const unsigned int* ub = src + (size_t)frame * FRAME_E + f0 + (t & 63) * 1024;
    int q = t >> 6;
#pragma unroll
    for (int i = 0; i < 4; i++) {
      uint4 v4 = *(const uint4*)(ub + q * 16 + i * 4);
      int fr = q * 16 + i * 4;
      int c = t & 63;
      unsigned int vv[4] = {v4.x, v4.y, v4.z, v4.w};
#pragma unroll
      for (int k = 0; k < 4; k++) {
        Bs[0][fr + k][c] = (short)(vv[k] & 0xffffu);
        Bs[1][fr + k][c] = (short)(vv[k] >> 16);
      }
    }
  }
  __syncthreads();
  int l = t & 63, wv = t >> 6;
  int n0 = wv * 16;
  int lrow = l & 15, loct = l >> 4;
  f32x4 accR[4], accI[4];
#pragma unroll
  for (int mt = 0; mt < 4; mt++) {
    accR[mt] = (f32x4){0.f, 0.f, 0.f, 0.f};
    accI[mt] = (f32x4){0.f, 0.f, 0.f, 0.f};
  }
#pragma unroll
  for (int kt = 0; kt < 2; kt++) {
    bf16x8 br = *(const bf16x8*)&Bs[0][n0 + lrow][kt * 32 + loct * 8];
    bf16x8 bi = *(const bf16x8*)&Bs[1][n0 + lrow][kt * 32 + loct * 8];
#pragma unroll
    for (int mt = 0; mt < 4; mt++) {
      bf16x8 ar = *(const bf16x8*)&Ams[0][mt * 16 + lrow][kt * 32 + loct * 8];
      bf16x8 ai = *(const bf16x8*)&Ams[1][mt * 16 + lrow][kt * 32 + loct * 8];
      bf16x8 an = *(const bf16x8*)&Ams[2][mt * 16 + lrow][kt * 32 + loct * 8];
      accR[mt] = __builtin_amdgcn_mfma_f32_16x16x32_bf16(ar, br, accR[mt], 0, 0, 0);
      accR[mt] = __builtin_amdgcn_mfma_f32_16x16x32_bf16(an, bi, accR[mt], 0, 0, 0);
      accI[mt] = __builtin_amdgcn_mfma_f32_16x16x32_bf16(ai, br, accI[mt], 0, 0, 0);
      accI[mt] = __builtin_amdgcn_mfma_f32_16x16x32_bf16(ar, bi, accI[mt], 0, 0, 0);
    }
  }
  unsigned int* db = dst + (size_t)frame * FRAME_E;
  int col = f0 + n0 + lrow;
  int hf = col & 31, w = col >> 5;
  unsigned int packed[4][4];
#pragma unroll
  for (int mt = 0; mt < 4; mt++) {
#pragma unroll
    for (int r = 0; r < 4; r++) {
      int o = mt * 16 + loct * 4 + r;
      float vr = accR[mt][r], vi = accI[mt][r];
      if (apply_gb) {
        if (w == 0) { vr += bbr[o]; vi += bbi[o]; }
        float g = gam[o * 32 + hf];
        vr *= g; vi *= g;
      }
      unsigned int u = packbf(vr, vi);
      packed[mt][r] = u;
      db[o * 1024 + col] = u;
    }
  }
  if (!apply_gb) {
    // ---- freq-domain LN stats over this (frame, 2-w) block ----
    __syncthreads();  // all LDS reads done; reuse sm
    unsigned int* Ts = (unsigned int*)sm;      // [64][65]
    float* red = (float*)(sm + 13824);         // cross-wave reduce
    int fl = n0 + lrow;
#pragma unroll
    for (int mt = 0; mt < 4; mt++)
#pragma unroll
      for (int r = 0; r < 4; r++) {
        int o = mt * 16 + loct * 4 + r;
        Ts[o * 65 + fl] = packed[mt][r];
      }
    __syncthreads();
    float q = 0.f, rp = 0.f, s1 = 0.f, s1b = 0.f;
    int oo = t >> 2;
    float bco = bcr[oo];
#pragma unroll
    for (int j = 0; j < 16; j++) {
      int flj = (t & 3) * 16 + j;
      unsigned int z = Ts[oo * 65 + flj];
      int pfl = (flj & 32) | ((32 - (flj & 31)) & 31);
      unsigned int zp = Ts[oo * 65 + pfl];
      float zr = bf2f_lo(z), zi = bf2f_hi(z);
      float pr = bf2f_lo(zp), pi = bf2f_hi(zp);
      q += zr * zr + zi * zi;
      rp += zr * pr - zi * pi;
      if ((flj & 31) == 0) { s1 += zr; s1b += bco * zr; }
    }
#pragma unroll
    for (int off = 32; off > 0; off >>= 1) {
      q   += __shfl_down(q, off);
      rp  += __shfl_down(rp, off);
      s1  += __shfl_down(s1, off);
      s1b += __shfl_down(s1b, off);
    }
    if (l == 0) {
      red[wv * 4 + 0] = q; red[wv * 4 + 1] = rp;
      red[wv * 4 + 2] = s1; red[wv * 4 + 3] = s1b;
    }
    __syncthreads();
    if (t == 0) {
      float tq = 0, trp = 0, ts1 = 0, ts1b = 0;
      for (int k = 0; k < 4; k++) {
        tq += red[k * 4 + 0]; trp += red[k * 4 + 1];
        ts1 += red[k * 4 + 2]; ts1b += red[k * 4 + 3];
      }
      atomicAdd(&statsRaw[frame * 4 + 0], tq);
      atomicAdd(&statsRaw[frame * 4 + 1], trp);
      atomicAdd(&statsRaw[frame * 4 + 2], ts1);
      atomicAdd(&statsRaw[frame * 4 + 3], ts1b);
    }
  }
}

// ---------------- linear recurrence over L, in place (uint2, fp32 state) ----
__global__ __launch_bounds__(256) void k_scan(unsigned int* __restrict__ buf,
                                              const c32* __restrict__ lamb) {
  int q = blockIdx.x * 256 + threadIdx.x;  // 0..65535
  int b = q >> 15;
  int e2 = (q & 32767) * 2;
  int c = e2 >> 10, hf = e2 & 31;
  float2 L0 = lamb[c * 32 + hf];
  float2 L1 = lamb[c * 32 + hf + 1];
  float a0r = 0.f, a0i = 0.f, a1r = 0.f, a1i = 0.f;
  uint2* p = (uint2*)(buf + (size_t)b * 128 * FRAME_E + e2);
#pragma unroll 8
  for (int l = 0; l < 128; l++) {
    uint2 v = p[(size_t)l * (FRAME_E / 2)];
    float n0r = L0.x * a0r - L0.y * a0i + bf2f_lo(v.x);
    float n0i = L0.x * a0i + L0.y * a0r + bf2f_hi(v.x);
    float n1r = L1.x * a1r - L1.y * a1i + bf2f_lo(v.y);
    float n1i = L1.x * a1i + L1.y * a1r + bf2f_hi(v.y);
    a0r = n0r; a0i = n0i; a1r = n1r; a1i = n1i;
    p[(size_t)l * (FRAME_E / 2)] = make_uint2(packbf(a0r, a0i), packbf(a1r, a1i));
  }
}

// ---------------- last_hidden: DFT along W of state at l=127, real part only
__global__ __launch_bounds__(256) void k_last2(const unsigned int* __restrict__ buf,
                                               float* __restrict__ out2) {
  const float PI = 3.14159265358979323846f;
  int idx = blockIdx.x * 256 + threadIdx.x;  // [0, 131072)
  int wf = idx & 31;
  int hf = (idx >> 5) & 31;
  int c  = (idx >> 10) & 63;
  int b  = idx >> 16;
  const unsigned int* s =
      buf + (size_t)(b * 128 + 127) * FRAME_E + c * 1024 + hf;
  float sr = 0.f;
  for (int w2 = 0; w2 < 32; w2++) {
    unsigned int v = s[w2 * 32];
    int m = (w2 * wf) & 31;
    float ang = -(PI / 16.0f) * (float)m;
    float sn, cs; sincosf(ang, &sn, &cs);
    sr += bf2f_lo(v) * cs - bf2f_hi(v) * sn;
  }
  out2[idx] = sr;
}

// ---------------- stats finalize: raw sums -> (mean, rstd) per frame --------
__global__ __launch_bounds__(256) void k_stats(const float* __restrict__ statsRaw,
                                               const float* __restrict__ bcr,
                                               float2* __restrict__ stats2) {
  int f = threadIdx.x;  // 256 frames
  float Bsum = 0.f, Bsq = 0.f;
  for (int o = 0; o < 64; o++) { float b = bcr[o]; Bsum += b; Bsq += b * b; }
  float q   = statsRaw[f * 4 + 0];
  float rp  = statsRaw[f * 4 + 1];
  float s1  = statsRaw[f * 4 + 2];
  float s1b = statsRaw[f * 4 + 3];
  float mean = (s1 + 1024.f * Bsum) * (1.0f / 65536.0f);
  float ex2 = ((rp + q) * (1.0f / 64.0f) + 2.f * s1b + 1024.f * Bsq) *
              (1.0f / 65536.0f);
  float var = ex2 - mean * mean;
  if (var < 0.f) var = 0.f;
  stats2[f] = make_float2(mean, rsqrtf(var + 1e-5f));
}

// ---------------- MFMA inverse DFT along H + bias + LayerNorm + residual ----
// in: t[p][w*32+hf] packed bf16c; out1[p][y*32+w] final (normalized + x)
__global__ __launch_bounds__(256) void k_idft_ln(
    const unsigned int* __restrict__ tbuf, const unsigned short* __restrict__ FIr,
    const unsigned short* __restrict__ FIn, const float2* __restrict__ stats2,
    const float* __restrict__ bcr, const float* __restrict__ lw,
    const float* __restrict__ lb, const float* __restrict__ x,
    float* __restrict__ out1) {
  __shared__ __align__(16) short FAr[32][40], FAn[32][40];
  __shared__ __align__(16) short Br[32][40], Bi[32][40];
  int p = blockIdx.x;  // frame*64 + o
  int t = threadIdx.x;
  int frame = p >> 6, o = p & 63;
  const unsigned int* tp = tbuf + (size_t)p * 1024;
  for (int i = t; i < 1024; i += 256) {
    int row = i >> 5, colk = i & 31;
    FAr[row][colk] = (short)FIr[i];
    FAn[row][colk] = (short)FIn[i];
    unsigned int v = tp[i];  // i = w*32+hf
    Br[row][colk] = (short)(v & 0xffffu);
    Bi[row][colk] = (short)(v >> 16);
  }
  __syncthreads();
  int wv = t >> 6, l = t & 63;
  int ty = wv >> 1, tw = wv & 1;
  int lrow = l & 15, loct = l >> 4;
  bf16x8 a_r = *(const bf16x8*)&FAr[ty * 16 + lrow][loct * 8];
  bf16x8 a_n = *(const bf16x8*)&FAn[ty * 16 + lrow][loct * 8];
  bf16x8 b_r = *(const bf16x8*)&Br[tw * 16 + lrow][loct * 8];
  bf16x8 b_i = *(const bf16x8*)&Bi[tw * 16 + lrow][loct * 8];
  f32x4 acc = (f32x4){0.f, 0.f, 0.f, 0.f};
  acc = __builtin_amdgcn_mfma_f32_16x16x32_bf16(a_r, b_r, acc, 0, 0, 0);
  acc = __builtin_amdgcn_mfma_f32_16x16x32_bf16(a_n, b_i, acc, 0, 0, 0);
  float2 st = stats2[frame];
  float mean = st.x, rstd = st.y;
  float bias = bcr[o];
  int w = tw * 16 + lrow;
  const float* lwp = lw + o * 1024;
  const float* lbp = lb + o * 1024;
  const float* xp = x + (size_t)p * 1024;
  float* op = out1 + (size_t)p * 1024;
#pragma unroll
  for (int r = 0; r < 4; r++) {
    int yy = ty * 16 + loct * 4 + r;
    int ofs = yy * 32 + w;
    float val = acc[r] + bias;
    op[ofs] = (val - mean) * rstd * lwp[ofs] + lbp[ofs] + xp[ofs];
  }
}

extern "C" void kernel_launch(void* const* d_in, const int* in_sizes, int n_in,
                              void* d_out, int out_size, void* d_ws,
                              size_t ws_size, hipStream_t stream) {
  const float* x   = (const float*)d_in[0];
  const float* pl  = (const float*)d_in[1];
  const float* Wbr = (const float*)d_in[2];
  const float* Wbi = (const float*)d_in[3];
  const float* bbr = (const float*)d_in[4];
  const float* bbi = (const float*)d_in[5];
  const float* Wcr = (const float*)d_in[6];
  const float* Wci = (const float*)d_in[7];
  const float* bcr = (const float*)d_in[8];
  // d_in[9] = bc_i: unused (imag discarded by .real)
  const float* lw  = (const float*)d_in[10];
  const float* lb  = (const float*)d_in[11];

  float* out1 = (float*)d_out;
  float* out2 = out1 + NTOT;  // real-cast last_hidden: 131072 floats

  unsigned int* A = (unsigned int*)d_ws;  // 67.1 MB packed bf16c
  unsigned int* B = A + NTOT;             // 67.1 MB packed bf16c
  unsigned short* MbR = (unsigned short*)(B + NTOT);
  unsigned short* MbI = MbR + 4096;
  unsigned short* MbN = MbI + 4096;
  unsigned short* McR = MbN + 4096;
  unsigned short* McI = McR + 4096;
  unsigned short* McN = McI + 4096;
  c32* lamb  = (c32*)(McN + 4096);
  float* gam = (float*)(lamb + 2048);
  c32* Ffwd  = (c32*)(gam + 2048);
  unsigned short* FIr = (unsigned short*)(Ffwd + 1024);
  unsigned short* FIn = FIr + 1024;
  float* statsRaw = (float*)(FIn + 1024);   // 256*4 floats
  float2* stats2 = (float2*)(statsRaw + 1024);

  hipMemsetAsync(statsRaw, 0, 1024 * sizeof(float), stream);
  k_prep<<<48, 256, 0, stream>>>(pl, Wbr, Wbi, Wcr, Wci, MbR, MbI, MbN, McR,
                                 McI, McN, lamb, gam, Ffwd, FIr, FIn);
  k_dfth<<<16384, 256, 0, stream>>>(x, A, Ffwd);
  k_gemm<<<dim3(16, 256), 256, 0, stream>>>(A, B, MbR, MbI, MbN, gam, bbr,
                                            bbi, bcr, statsRaw, 1);
  k_scan<<<256, 256, 0, stream>>>(B, lamb);
  k_last2<<<512, 256, 0, stream>>>(B, out2);
  k_gemm<<<dim3(16, 256), 256, 0, stream>>>(B, A, McR, McI, McN, gam, bbr,
                                            bbi, bcr, statsRaw, 0);
  k_stats<<<1, 256, 0, stream>>>(statsRaw, bcr, stats2);
  k_idft_ln<<<16384, 256, 0, stream>>>(A, FIr, FIn, stats2, bcr, lw, lb, x,
                                       out1);
}